// Round 4
// baseline (107.862 us; speedup 1.0000x reference)
//
#include <hip/hip_runtime.h>
#include <hip/hip_bf16.h>
#include <math.h>

#define N 2048
#define NC 8

// ws layout:
//   [0, 64)               : double acc[8]          (zeroed by k_prep block 0)
//   [64, 64+128K)          : float2 pack[8][2048]   {s/ln2, A/ln2} (k_scanpack)
//   [64+128K, 64+192K)     : int    lohi[8][2048]   (lo | hi<<16, per ORIGINAL row)
//   [64+192K, +4)          : unsigned counter       (ticket for fused finalize)
//   [64+192K+64, +64K)     : int    rankbuf[8][2048] (score-rank, k_prep -> k_scanpack)

#if __has_builtin(__builtin_amdgcn_exp2f)
__device__ __forceinline__ float fexp2(float x) { return __builtin_amdgcn_exp2f(x); }
#else
__device__ __forceinline__ float fexp2(float x) { return exp2f(x); }
#endif
#if __has_builtin(__builtin_amdgcn_logf)
__device__ __forceinline__ float flog2(float x) { return __builtin_amdgcn_logf(x); }
#else
__device__ __forceinline__ float flog2(float x) { return log2f(x); }
#endif

#define INV_LN2 1.4426950408889634f
#define LN2_D   0.6931471805599453
#define CLAMP2  (-144.26950408889634f)   /* -100/ln2 : clamp in log2 domain */

// ---------------- Kernel 1: score-rank + counting-rank GT ---------------------
// R3 EXPERIMENT: the O(n^2) f64 |s_j - s_i| accumulation is replaced by a
// score-RANK counting loop (u64 cmp+add, ~6 cyc/elem vs ~15-20 for the f64
// abs-diff chain). A[j] is reconstructed exactly in k_scanpack via
//   A[j] = s_j*(2 r_j - n) + T - 2*P(r_j)   (f64 prefix of sorted scores).
// blocks [0,256):   rank of s_j among column scores -> rankbuf
// blocks [256,512): counting-rank GT windows -> lohi   (UNCHANGED)
__global__ __launch_bounds__(256) void k_prep(const float* __restrict__ logits,
                                              const float* __restrict__ dur,
                                              const int* __restrict__ ev,
                                              int* __restrict__ rankbuf,
                                              int* __restrict__ lohi,
                                              double* __restrict__ acc,
                                              unsigned* __restrict__ counter) {
    __shared__ unsigned long long keys[N];   // 16 KB  (both halves)
    __shared__ int pr[256], pv[256];         // 2 KB

    int b = blockIdx.x;
    int tid = threadIdx.x;

    if (b == 0) {  // zero accumulators + ticket for k_bce (stream-ordered)
        if (tid < 8) acc[tid] = 0.0;
        else if (tid == 8) counter[0] = 0u;
    }

    if (b < 256) {
        // ---- score-rank: key = (ordered_bits(s)<<32) | i  (strict total order,
        //      index tie-break => permutation even under bitwise score ties) ----
        int col = b >> 5, chunk = b & 31;
        for (int k = 0; k < N / 256; ++k) {
            int i = tid + k * 256;
            unsigned bb = __float_as_uint(logits[i * NC + col]);
            unsigned ou = (bb & 0x80000000u) ? ~bb : (bb | 0x80000000u); // monotone map
            keys[i] = ((unsigned long long)ou << 32) | (unsigned)i;
        }
        __syncthreads();
        int jl = tid & 63, slice = tid >> 6;
        int j = chunk * 64 + jl;
        unsigned long long kj = keys[j];
        int base = slice * 512;
        int r0 = 0, r1 = 0, r2 = 0, r3 = 0;
        #pragma unroll 4
        for (int i = 0; i < 512; i += 4) {
            r0 += (keys[base + i]     < kj);
            r1 += (keys[base + i + 1] < kj);
            r2 += (keys[base + i + 2] < kj);
            r3 += (keys[base + i + 3] < kj);
        }
        pr[tid] = (r0 + r1) + (r2 + r3);
        __syncthreads();
        if (tid < 64) {
            int r = ((pr[tid] + pr[tid + 64]) + pr[tid + 128]) + pr[tid + 192];
            rankbuf[col * N + j] = r;
        }
    } else {
        // ---- counting-rank GT windows (UNCHANGED) ----
        int b2 = b - 256;
        int col = b2 >> 5, chunk = b2 & 31;
        for (int k = 0; k < N / 256; ++k) {
            int i = tid + k * 256;
            unsigned int db = __float_as_uint(dur[i * NC + col]);  // dur in [0,1)
            int e = ev[i * NC + col];
            keys[i] = ((unsigned long long)db << 32) | (unsigned int)((i << 1) | e);
        }
        __syncthreads();
        int jl = tid & 63, slice = tid >> 6;
        int j = chunk * 64 + jl;
        unsigned long long kj = keys[j];
        int base = slice * 512;
        int rank = 0, evlt = 0;
        #pragma unroll 4
        for (int i = 0; i < 512; ++i) {
            unsigned long long ki = keys[base + i];
            int lt = (ki < kj) ? 1 : 0;
            rank += lt;
            evlt += lt & (int)(ki & 1ull);
        }
        pr[tid] = rank;
        pv[tid] = evlt;
        __syncthreads();
        if (tid < 64) {
            int r = ((pr[tid] + pr[tid + 64]) + pr[tid + 128]) + pr[tid + 192];
            int v = ((pv[tid] + pv[tid + 64]) + pv[tid + 128]) + pv[tid + 192];
            int e = (int)(kj & 1ull);
            int hi = e ? (r + 1) : N;
            lohi[col * N + j] = v | (hi << 16);
        }
    }
}

// ---------------- Kernel 1.5: scatter-by-rank + f64 scan + A formula ----------
// 8 blocks (one per column), 256 threads. ~2 us serial cost.
// pex[q] = sum_{p<q} sorted_s[p] (exclusive, f64); T = total.
// A[j] = s_j*(2 r_j - N) + T - 2*pex[r_j]  — exact to f64 rounding, identical
// after the f32 round to the old direct f64 accumulation (few-ulp f64 delta).
__global__ __launch_bounds__(256) void k_scanpack(const float* __restrict__ logits,
                                                  const int* __restrict__ rankbuf,
                                                  float2* __restrict__ pack) {
    int col = blockIdx.x;            // 0..7
    __shared__ float  ssort[N];      // 8 KB  sorted scores
    __shared__ double pex[N];        // 16 KB exclusive prefix
    __shared__ double wsum[4];       // per-wave chunk totals
    int tid = threadIdx.x;
    int lane = tid & 63, wave = tid >> 6;

    // load (coalesced stride-8, same pattern as k_prep) + scatter by rank
    float sv[8];
    int   rv[8];
    #pragma unroll
    for (int k = 0; k < 8; ++k) {
        int j = tid + (k << 8);
        sv[k] = logits[j * NC + col];
        rv[k] = rankbuf[col * N + j];
        ssort[rv[k]] = sv[k];
    }
    __syncthreads();

    // thread t owns sorted chunk [8t, 8t+8): serial f64 local scan
    double loc[8];
    double c = 0.0;
    #pragma unroll
    for (int k = 0; k < 8; ++k) {
        loc[k] = c;
        c += (double)ssort[tid * 8 + k];
    }
    // wave-level inclusive scan of chunk sums (f64 via 64-bit shfl)
    double inc = c;
    #pragma unroll
    for (int off = 1; off < 64; off <<= 1) {
        double y = __shfl_up(inc, off, 64);
        if (lane >= off) inc += y;
    }
    if (lane == 63) wsum[wave] = inc;
    __syncthreads();
    double woff = 0.0;
    #pragma unroll
    for (int w = 0; w < 4; ++w)
        if (w < wave) woff += wsum[w];
    double T = ((wsum[0] + wsum[1]) + (wsum[2] + wsum[3]));
    double exc = woff + (inc - c);   // exclusive prefix at own chunk start
    #pragma unroll
    for (int k = 0; k < 8; ++k) pex[tid * 8 + k] = exc + loc[k];
    __syncthreads();

    // A formula + pack write (coalesced by original j)
    #pragma unroll
    for (int k = 0; k < 8; ++k) {
        int j = tid + (k << 8);
        float s = sv[k];
        int   r = rv[k];
        double A = (double)s * (double)(2 * r - N) + T - 2.0 * pex[r];
        pack[col * N + j] = make_float2(s * INV_LN2, (float)A * INV_LN2);
    }
}

// ---------------- Kernel 2: softmax+BCE — BYTE-IDENTICAL to measured r12 ------
// (102.29 us total this session; one-variable discipline: only k_prep changed.)
__global__ __launch_bounds__(256) void k_bce(const float2* __restrict__ pack,
                                             const int* __restrict__ lohi,
                                             double* __restrict__ acc,
                                             unsigned* __restrict__ counter,
                                             float* __restrict__ out) {
    int col = blockIdx.x >> 7;   // 0..7
    int rg  = blockIdx.x & 127;  // 0..127 (16 rows each)
    __shared__ float4 sa4[N / 2];   // 16 KB, LIVE through all passes
    __shared__ double bsum[4];      // block reduction buffer
    int tid = threadIdx.x;
    int wave = tid >> 6, lane = tid & 63;

    const float4* p4 = (const float4*)(pack + (size_t)col * N);
    #pragma unroll
    for (int k = 0; k < 4; ++k) {
        int i = tid + (k << 8);
        sa4[i] = p4[i];
    }
    __syncthreads();

    int row0 = (rg << 4) + (wave << 2);
    float sc0 = (float)(N - 1 - 2 * row0);

    int lh[4];
    #pragma unroll
    for (int c = 0; c < 4; ++c) lh[c] = lohi[col * N + row0 + c];

    // pass 1: max of row 0 ONLY (m0 frame)
    float m = -INFINITY;
    #pragma unroll
    for (int k = 0; k < 16; ++k) {
        float4 q = sa4[lane + (k << 6)];
        float t0 = fmaf(sc0, q.x, -q.y);
        float t1 = fmaf(sc0, q.z, -q.w);
        m = fmaxf(m, fmaxf(t0, t1));
    }
    #pragma unroll
    for (int off = 32; off > 0; off >>= 1)
        m = fmaxf(m, __shfl_xor(m, off, 64));

    // pass 2: se_c = sum_j 2^(t_c - m0); rows 1..3 by incremental multiply
    float se0 = 0.0f, se1 = 0.0f, se2 = 0.0f, se3 = 0.0f;
    #pragma unroll
    for (int k = 0; k < 16; ++k) {
        float4 q = sa4[lane + (k << 6)];
        {
            float g = fexp2(-(q.x + q.x));
            float E = fexp2(fmaf(sc0, q.x, -q.y) - m);
            se0 += E; E *= g;
            se1 += E; E *= g;
            se2 += E; E *= g;
            se3 += E;
        }
        {
            float g = fexp2(-(q.z + q.z));
            float E = fexp2(fmaf(sc0, q.z, -q.w) - m);
            se0 += E; E *= g;
            se1 += E; E *= g;
            se2 += E; E *= g;
            se3 += E;
        }
    }
    #pragma unroll
    for (int off = 32; off > 0; off >>= 1) {
        se0 += __shfl_xor(se0, off, 64);
        se1 += __shfl_xor(se1, off, 64);
        se2 += __shfl_xor(se2, off, 64);
        se3 += __shfl_xor(se3, off, 64);
    }
    float se[4] = {se0, se1, se2, se3};

    float C2v[4], yv[4];
    unsigned lo[4], wl[4];
    double rbase = 0.0;
    #pragma unroll
    for (int c = 0; c < 4; ++c) {
        float L2 = flog2(se[c]);
        rbase -= 2048.0 * (double)L2;
        C2v[c] = CLAMP2 + L2;
        lo[c] = (unsigned)(lh[c] & 0xffff);
        wl[c] = (unsigned)((lh[c] >> 16) & 0xffff) - lo[c];
        yv[c] = 1.0f / (float)wl[c];
    }

    // pass 3: a1_c = sum max(log2(se_c - E_c), C2_c); a2_c = windowed (mx1-mx2)
    float a1[4] = {0.0f, 0.0f, 0.0f, 0.0f};
    float a2[4] = {0.0f, 0.0f, 0.0f, 0.0f};
    #pragma unroll
    for (int k = 0; k < 16; ++k) {
        float4 q = sa4[lane + (k << 6)];
        int j0 = (lane + (k << 6)) << 1;
        {
            float tsv = q.x + q.x;
            float g = fexp2(-tsv);
            float x = fmaf(sc0, q.x, -q.y) - m;
            float E = fexp2(x);
            #pragma unroll
            for (int c = 0; c < 4; ++c) {
                float mx2 = fmaxf(flog2(se[c] - E), C2v[c]);
                a1[c] += mx2;
                float mx1 = fmaxf(x, C2v[c]);
                float w = ((unsigned)(j0 - lo[c]) < wl[c]) ? (mx1 - mx2) : 0.0f;
                a2[c] += w;
                E *= g;
                x -= tsv;
            }
        }
        {
            float tsv = q.z + q.z;
            float g = fexp2(-tsv);
            float x = fmaf(sc0, q.z, -q.w) - m;
            float E = fexp2(x);
            #pragma unroll
            for (int c = 0; c < 4; ++c) {
                float mx2 = fmaxf(flog2(se[c] - E), C2v[c]);
                a1[c] += mx2;
                float mx1 = fmaxf(x, C2v[c]);
                float w = ((unsigned)(j0 + 1 - lo[c]) < wl[c]) ? (mx1 - mx2) : 0.0f;
                a2[c] += w;
                E *= g;
                x -= tsv;
            }
        }
    }
    float r = 0.0f;
    #pragma unroll
    for (int c = 0; c < 4; ++c) r += fmaf(yv[c], a2[c], a1[c]);
    #pragma unroll
    for (int off = 32; off > 0; off >>= 1)
        r += __shfl_xor(r, off, 64);

    if (lane == 0) bsum[wave] = rbase + (double)r;
    __syncthreads();
    if (tid == 0) {
        double tot = (bsum[0] + bsum[1]) + (bsum[2] + bsum[3]);
        atomicAdd(&acc[col], LN2_D * tot);
        __threadfence();
        unsigned old = atomicAdd(counter, 1u);
        if (old == (unsigned)(NC * 128 - 1)) {  // last of 1024 blocks
            __threadfence();
            float ssum = 0.0f;
            int cnt = 0;
            for (int c = 0; c < NC; ++c) {
                double av2 = atomicAdd(&acc[c], 0.0);  // device-scope read
                float lc = (float)(-av2 / ((double)N * (double)N));
                if (lc > 0.0f) { ssum += lc; cnt++; }
            }
            out[0] = ssum / (float)(cnt > 0 ? cnt : 1);
        }
    }
}

extern "C" void kernel_launch(void* const* d_in, const int* in_sizes, int n_in,
                              void* d_out, int out_size, void* d_ws, size_t ws_size,
                              hipStream_t stream) {
    const float* logits    = (const float*)d_in[0];
    const int*   events    = (const int*)d_in[1];
    const float* durations = (const float*)d_in[2];
    float* out = (float*)d_out;

    char* ws = (char*)d_ws;
    double*   acc     = (double*)ws;
    float2*   pack    = (float2*)(ws + 64);
    int*      lohi    = (int*)(ws + 64 + (size_t)NC * N * sizeof(float2));
    unsigned* counter = (unsigned*)(ws + 64 + (size_t)NC * N * (sizeof(float2) + sizeof(int)));
    int*      rankbuf = (int*)(ws + 64 + (size_t)NC * N * (sizeof(float2) + sizeof(int)) + 64);

    k_prep<<<dim3(512), 256, 0, stream>>>(logits, durations, events, rankbuf, lohi, acc, counter);
    k_scanpack<<<dim3(NC), 256, 0, stream>>>(logits, rankbuf, pack);
    k_bce<<<dim3(NC * 128), 256, 0, stream>>>(pack, lohi, acc, counter, out);
}

// Round 5
// 98.426 us; speedup vs baseline: 1.0959x; 1.0959x over previous
//
#include <hip/hip_runtime.h>
#include <hip/hip_bf16.h>
#include <math.h>

#define N 2048
#define NC 8

// ws layout:
//   [0, 64)              : double acc[8]          (zeroed by k_prep block 0)
//   [64, 64+128K)        : float2 pack[8][2048]   {s/ln2, A/ln2} packed by k_prep
//   [64+128K, 64+192K)   : int    lohi[8][2048]   (lo | hi<<16, per ORIGINAL row)
//   [64+192K, +4)        : unsigned counter       (ticket for fused finalize)

#if __has_builtin(__builtin_amdgcn_exp2f)
__device__ __forceinline__ float fexp2(float x) { return __builtin_amdgcn_exp2f(x); }
#else
__device__ __forceinline__ float fexp2(float x) { return exp2f(x); }
#endif
#if __has_builtin(__builtin_amdgcn_logf)
__device__ __forceinline__ float flog2(float x) { return __builtin_amdgcn_logf(x); }
#else
__device__ __forceinline__ float flog2(float x) { return log2f(x); }
#endif

#define INV_LN2 1.4426950408889634f
#define LN2_D   0.6931471805599453
#define CLAMP2  (-144.26950408889634f)   /* -100/ln2 : clamp in log2 domain */

// ---------------- Kernel 1: fused A-sum + counting-rank GT + packing ----------
// R5 EXPERIMENT (one variable): occupancy of k_prep 2x. Grid 512 -> 1024 blocks
// (4 blocks/CU -> 4 waves/SIMD instead of 2). Each block now covers 32 j's with
// 8 i-slices of 256 (was 64 j's, 4 slices of 512). Per-block work halves.
// Tests the latency-bound-k_prep hypothesis: serial f64-add / u64-cmp chains at
// 2 waves/SIMD may be latency-exposed. f64 summation only REGROUPS (R4 showed
// f64 regrouping of A leaves absmax at 0.0); integer ranks grouping-invariant.
// k_scanpack (R4, regressed +5.6us) deleted; direct f64 asum restored.
// blocks [0,512):    A[j] = sum_i |s_j - s_i| ; write pack[col][j] = {s,A}/ln2
// blocks [512,1024): counting-rank windows -> lohi
__global__ __launch_bounds__(256) void k_prep(const float* __restrict__ logits,
                                              const float* __restrict__ dur,
                                              const int* __restrict__ ev,
                                              float2* __restrict__ pack,
                                              int* __restrict__ lohi,
                                              double* __restrict__ acc,
                                              unsigned* __restrict__ counter) {
    __shared__ float s[N];                   // 8 KB   (asum)
    __shared__ double part[256];             // 2 KB   (asum)
    __shared__ unsigned long long keys[N];   // 16 KB  (sortgt)
    __shared__ int pr[256], pv[256];         // 2 KB   (sortgt)

    int b = blockIdx.x;
    int tid = threadIdx.x;

    if (b == 0) {  // zero accumulators + ticket for k_bce (stream-ordered)
        if (tid < 8) acc[tid] = 0.0;
        else if (tid == 8) counter[0] = 0u;
    }

    if (b < 512) {
        // ---- A-sum, 32 j's per block, 8 i-slices of 256 (f64: exactness) ----
        int col = b >> 6, chunk = b & 63;
        for (int k = 0; k < N / 256; ++k) {
            int i = tid + k * 256;
            s[i] = logits[i * NC + col];
        }
        __syncthreads();
        int jl = tid & 31, slice = tid >> 5;   // 32 j-lanes x 8 slices
        int j = chunk * 32 + jl;
        float sj = s[j];
        int base = slice * 256;
        double a0 = 0.0, a1 = 0.0, a2 = 0.0, a3 = 0.0;
        #pragma unroll 2
        for (int i = 0; i < 256; i += 4) {
            a0 += (double)fabsf(sj - s[base + i]);
            a1 += (double)fabsf(sj - s[base + i + 1]);
            a2 += (double)fabsf(sj - s[base + i + 2]);
            a3 += (double)fabsf(sj - s[base + i + 3]);
        }
        part[tid] = (a0 + a1) + (a2 + a3);
        __syncthreads();
        if (tid < 32) {
            double v = ((part[tid]       + part[tid + 32])  + (part[tid + 64]  + part[tid + 96])) +
                       ((part[tid + 128] + part[tid + 160]) + (part[tid + 192] + part[tid + 224]));
            pack[col * N + j] = make_float2(sj * INV_LN2, (float)v * INV_LN2);
        }
    } else {
        // ---- counting-rank GT windows, 32 j's per block, 8 slices of 256 ----
        // key = (dur_bits<<32)|(i<<1)|e : ascending u64 == stable ascending by d
        int b2 = b - 512;
        int col = b2 >> 6, chunk = b2 & 63;
        for (int k = 0; k < N / 256; ++k) {
            int i = tid + k * 256;
            unsigned int db = __float_as_uint(dur[i * NC + col]);  // dur in [0,1)
            int e = ev[i * NC + col];
            keys[i] = ((unsigned long long)db << 32) | (unsigned int)((i << 1) | e);
        }
        __syncthreads();
        int jl = tid & 31, slice = tid >> 5;
        int j = chunk * 32 + jl;
        unsigned long long kj = keys[j];
        int base = slice * 256;
        int rank = 0, evlt = 0;
        #pragma unroll 4
        for (int i = 0; i < 256; ++i) {
            unsigned long long ki = keys[base + i];
            int lt = (ki < kj) ? 1 : 0;
            rank += lt;
            evlt += lt & (int)(ki & 1ull);
        }
        pr[tid] = rank;
        pv[tid] = evlt;
        __syncthreads();
        if (tid < 32) {
            int r = ((pr[tid]       + pr[tid + 32])  + (pr[tid + 64]  + pr[tid + 96])) +
                    ((pr[tid + 128] + pr[tid + 160]) + (pr[tid + 192] + pr[tid + 224]));
            int v = ((pv[tid]       + pv[tid + 32])  + (pv[tid + 64]  + pv[tid + 96])) +
                    ((pv[tid + 128] + pv[tid + 160]) + (pv[tid + 192] + pv[tid + 224]));
            int e = (int)(kj & 1ull);
            int hi = e ? (r + 1) : N;
            lohi[col * N + j] = v | (hi << 16);
        }
    }
}

// ---------------- Kernel 2: softmax+BCE — BYTE-IDENTICAL to measured r12 ------
// (102.29 us total; one-variable discipline: only k_prep changed this round.)
__global__ __launch_bounds__(256) void k_bce(const float2* __restrict__ pack,
                                             const int* __restrict__ lohi,
                                             double* __restrict__ acc,
                                             unsigned* __restrict__ counter,
                                             float* __restrict__ out) {
    int col = blockIdx.x >> 7;   // 0..7
    int rg  = blockIdx.x & 127;  // 0..127 (16 rows each)
    __shared__ float4 sa4[N / 2];   // 16 KB, LIVE through all passes
    __shared__ double bsum[4];      // block reduction buffer
    int tid = threadIdx.x;
    int wave = tid >> 6, lane = tid & 63;

    const float4* p4 = (const float4*)(pack + (size_t)col * N);
    #pragma unroll
    for (int k = 0; k < 4; ++k) {
        int i = tid + (k << 8);
        sa4[i] = p4[i];
    }
    __syncthreads();

    int row0 = (rg << 4) + (wave << 2);
    float sc0 = (float)(N - 1 - 2 * row0);

    int lh[4];
    #pragma unroll
    for (int c = 0; c < 4; ++c) lh[c] = lohi[col * N + row0 + c];

    // pass 1: max of row 0 ONLY (m0 frame)
    float m = -INFINITY;
    #pragma unroll
    for (int k = 0; k < 16; ++k) {
        float4 q = sa4[lane + (k << 6)];
        float t0 = fmaf(sc0, q.x, -q.y);
        float t1 = fmaf(sc0, q.z, -q.w);
        m = fmaxf(m, fmaxf(t0, t1));
    }
    #pragma unroll
    for (int off = 32; off > 0; off >>= 1)
        m = fmaxf(m, __shfl_xor(m, off, 64));

    // pass 2: se_c = sum_j 2^(t_c - m0); rows 1..3 by incremental multiply
    float se0 = 0.0f, se1 = 0.0f, se2 = 0.0f, se3 = 0.0f;
    #pragma unroll
    for (int k = 0; k < 16; ++k) {
        float4 q = sa4[lane + (k << 6)];
        {
            float g = fexp2(-(q.x + q.x));
            float E = fexp2(fmaf(sc0, q.x, -q.y) - m);
            se0 += E; E *= g;
            se1 += E; E *= g;
            se2 += E; E *= g;
            se3 += E;
        }
        {
            float g = fexp2(-(q.z + q.z));
            float E = fexp2(fmaf(sc0, q.z, -q.w) - m);
            se0 += E; E *= g;
            se1 += E; E *= g;
            se2 += E; E *= g;
            se3 += E;
        }
    }
    #pragma unroll
    for (int off = 32; off > 0; off >>= 1) {
        se0 += __shfl_xor(se0, off, 64);
        se1 += __shfl_xor(se1, off, 64);
        se2 += __shfl_xor(se2, off, 64);
        se3 += __shfl_xor(se3, off, 64);
    }
    float se[4] = {se0, se1, se2, se3};

    float C2v[4], yv[4];
    unsigned lo[4], wl[4];
    double rbase = 0.0;
    #pragma unroll
    for (int c = 0; c < 4; ++c) {
        float L2 = flog2(se[c]);
        rbase -= 2048.0 * (double)L2;
        C2v[c] = CLAMP2 + L2;
        lo[c] = (unsigned)(lh[c] & 0xffff);
        wl[c] = (unsigned)((lh[c] >> 16) & 0xffff) - lo[c];
        yv[c] = 1.0f / (float)wl[c];
    }

    // pass 3: a1_c = sum max(log2(se_c - E_c), C2_c); a2_c = windowed (mx1-mx2)
    float a1[4] = {0.0f, 0.0f, 0.0f, 0.0f};
    float a2[4] = {0.0f, 0.0f, 0.0f, 0.0f};
    #pragma unroll
    for (int k = 0; k < 16; ++k) {
        float4 q = sa4[lane + (k << 6)];
        int j0 = (lane + (k << 6)) << 1;
        {
            float tsv = q.x + q.x;
            float g = fexp2(-tsv);
            float x = fmaf(sc0, q.x, -q.y) - m;
            float E = fexp2(x);
            #pragma unroll
            for (int c = 0; c < 4; ++c) {
                float mx2 = fmaxf(flog2(se[c] - E), C2v[c]);
                a1[c] += mx2;
                float mx1 = fmaxf(x, C2v[c]);
                float w = ((unsigned)(j0 - lo[c]) < wl[c]) ? (mx1 - mx2) : 0.0f;
                a2[c] += w;
                E *= g;
                x -= tsv;
            }
        }
        {
            float tsv = q.z + q.z;
            float g = fexp2(-tsv);
            float x = fmaf(sc0, q.z, -q.w) - m;
            float E = fexp2(x);
            #pragma unroll
            for (int c = 0; c < 4; ++c) {
                float mx2 = fmaxf(flog2(se[c] - E), C2v[c]);
                a1[c] += mx2;
                float mx1 = fmaxf(x, C2v[c]);
                float w = ((unsigned)(j0 + 1 - lo[c]) < wl[c]) ? (mx1 - mx2) : 0.0f;
                a2[c] += w;
                E *= g;
                x -= tsv;
            }
        }
    }
    float r = 0.0f;
    #pragma unroll
    for (int c = 0; c < 4; ++c) r += fmaf(yv[c], a2[c], a1[c]);
    #pragma unroll
    for (int off = 32; off > 0; off >>= 1)
        r += __shfl_xor(r, off, 64);

    if (lane == 0) bsum[wave] = rbase + (double)r;
    __syncthreads();
    if (tid == 0) {
        double tot = (bsum[0] + bsum[1]) + (bsum[2] + bsum[3]);
        atomicAdd(&acc[col], LN2_D * tot);
        __threadfence();
        unsigned old = atomicAdd(counter, 1u);
        if (old == (unsigned)(NC * 128 - 1)) {  // last of 1024 blocks
            __threadfence();
            float ssum = 0.0f;
            int cnt = 0;
            for (int c = 0; c < NC; ++c) {
                double av2 = atomicAdd(&acc[c], 0.0);  // device-scope read
                float lc = (float)(-av2 / ((double)N * (double)N));
                if (lc > 0.0f) { ssum += lc; cnt++; }
            }
            out[0] = ssum / (float)(cnt > 0 ? cnt : 1);
        }
    }
}

extern "C" void kernel_launch(void* const* d_in, const int* in_sizes, int n_in,
                              void* d_out, int out_size, void* d_ws, size_t ws_size,
                              hipStream_t stream) {
    const float* logits    = (const float*)d_in[0];
    const int*   events    = (const int*)d_in[1];
    const float* durations = (const float*)d_in[2];
    float* out = (float*)d_out;

    char* ws = (char*)d_ws;
    double*   acc     = (double*)ws;
    float2*   pack    = (float2*)(ws + 64);
    int*      lohi    = (int*)(ws + 64 + (size_t)NC * N * sizeof(float2));
    unsigned* counter = (unsigned*)(ws + 64 + (size_t)NC * N * (sizeof(float2) + sizeof(int)));

    k_prep<<<dim3(1024), 256, 0, stream>>>(logits, durations, events, pack, lohi, acc, counter);
    k_bce<<<dim3(NC * 128), 256, 0, stream>>>(pack, lohi, acc, counter, out);
}